// Round 6
// baseline (6656.297 us; speedup 1.0000x reference)
//
#include <hip/hip_runtime.h>

#define D 64
#define D4 16   // D/4 float4 per row

typedef float4 f4;

__device__ __forceinline__ float leaky02(float x) { return (x >= 0.f) ? x : 0.2f * x; }

__device__ __forceinline__ f4 f4add(f4 a, f4 b) {
    return make_float4(a.x + b.x, a.y + b.y, a.z + b.z, a.w + b.w);
}
__device__ __forceinline__ f4 f4fma(float s, f4 v, f4 a) {
    return make_float4(fmaf(s, v.x, a.x), fmaf(s, v.y, a.y), fmaf(s, v.z, a.z), fmaf(s, v.w, a.w));
}
__device__ __forceinline__ f4 f4scale(f4 a, float s) {
    return make_float4(a.x * s, a.y * s, a.z * s, a.w * s);
}

// ---------------- CSR build ----------------

__global__ __launch_bounds__(256) void hist_kernel(const int* __restrict__ dst,
                                                   int* __restrict__ cnt, int ne) {
    int e = blockIdx.x * blockDim.x + threadIdx.x;
    if (e < ne) atomicAdd(&cnt[dst[e]], 1);
}

#define SCAN_BS 256
__global__ __launch_bounds__(SCAN_BS) void scan1_kernel(const int* __restrict__ cnt,
                                                        int* __restrict__ incl,
                                                        int* __restrict__ partials, int n) {
    __shared__ int sm[SCAN_BS];
    int g = blockIdx.x * SCAN_BS + threadIdx.x;
    int v = (g < n) ? cnt[g] : 0;
    sm[threadIdx.x] = v;
    __syncthreads();
    for (int off = 1; off < SCAN_BS; off <<= 1) {
        int t = (threadIdx.x >= off) ? sm[threadIdx.x - off] : 0;
        __syncthreads();
        sm[threadIdx.x] += t;
        __syncthreads();
    }
    if (g < n) incl[g] = sm[threadIdx.x];
    if (threadIdx.x == SCAN_BS - 1) partials[blockIdx.x] = sm[threadIdx.x];
}

__global__ __launch_bounds__(1024) void scan2_kernel(int* __restrict__ partials, int nb) {
    __shared__ int sm[1024];
    int t = threadIdx.x;
    int v = (t < nb) ? partials[t] : 0;
    sm[t] = v;
    __syncthreads();
    for (int off = 1; off < 1024; off <<= 1) {
        int x = (t >= off) ? sm[t - off] : 0;
        __syncthreads();
        sm[t] += x;
        __syncthreads();
    }
    if (t < nb) partials[t] = sm[t] - v;   // exclusive
}

__global__ __launch_bounds__(SCAN_BS) void scan3_kernel(const int* __restrict__ cnt,
                                                        const int* __restrict__ incl,
                                                        const int* __restrict__ partials,
                                                        int* __restrict__ rowptr,
                                                        int* __restrict__ cursor, int n, int ne) {
    int g = blockIdx.x * SCAN_BS + threadIdx.x;
    if (g < n) {
        int rp = incl[g] - cnt[g] + partials[blockIdx.x];
        rowptr[g] = rp;
        cursor[g] = rp;
    }
    if (g == 0) rowptr[n] = ne;
}

__global__ __launch_bounds__(256) void fill_kernel(const int* __restrict__ src,
                                                   const int* __restrict__ dst,
                                                   int* __restrict__ cursor,
                                                   int* __restrict__ col, int ne) {
    int e = blockIdx.x * blockDim.x + threadIdx.x;
    if (e < ne) {
        int pos = atomicAdd(&cursor[dst[e]], 1);
        col[pos] = src[e];
    }
}

// ---------------- tiled 64x64 GEMM: out = in @ W.T (+bias) ----------------
// One wave per 64-node tile; lane (r=lane&7,c=lane>>3) owns 8 nodes x 8 outs.
// At/Wt staged transposed with XOR swizzle on bits 3..4 (+compile-time half
// swap for bit 2) -> <=2-way LDS banks everywhere; global I/O fully coalesced.

__device__ __forceinline__ void stage_T(float* __restrict__ T, const f4* __restrict__ g4,
                                        int lane, int valid_rows) {
    int kq = lane & 15, q = lane >> 4;
#pragma unroll
    for (int i = 0; i < 16; i++) {
        int row = i * 4 + q;
        f4 r = make_float4(0.f, 0.f, 0.f, 0.f);
        if (row < valid_rows) r = g4[(size_t)row * 16 + kq];
        int sw = (kq & 7) << 2;
        T[(kq * 4 + 0) * 64 + (row ^ sw)] = r.x;
        T[(kq * 4 + 1) * 64 + (row ^ sw)] = r.y;
        T[(kq * 4 + 2) * 64 + (row ^ sw)] = r.z;
        T[(kq * 4 + 3) * 64 + (row ^ sw)] = r.w;
    }
}

#define GEMM_CORE(At, Wt, acc, r, c)                                          \
    _Pragma("unroll")                                                         \
    for (int kq = 0; kq < 16; kq++) {                                         \
        const int sw = (kq & 7) << 2;                                         \
        const int sw24 = sw & 24;                                             \
        const bool swp = (sw & 4) != 0;                                       \
        const int aB = (r * 8) ^ sw24;                                        \
        const int wB = (c * 8) ^ sw24;                                        \
        _Pragma("unroll")                                                     \
        for (int j = 0; j < 4; j++) {                                         \
            const int k = kq * 4 + j;                                         \
            f4 alo = *(const f4*)&At[k * 64 + aB];                            \
            f4 ahi = *(const f4*)&At[k * 64 + aB + 4];                        \
            f4 wlo = *(const f4*)&Wt[k * 64 + wB];                            \
            f4 whi = *(const f4*)&Wt[k * 64 + wB + 4];                        \
            f4 A0 = swp ? ahi : alo, A1 = swp ? alo : ahi;                    \
            f4 W0 = swp ? whi : wlo, W1 = swp ? wlo : whi;                    \
            float av[8] = {A0.x, A0.y, A0.z, A0.w, A1.x, A1.y, A1.z, A1.w};   \
            float wv[8] = {W0.x, W0.y, W0.z, W0.w, W1.x, W1.y, W1.z, W1.w};   \
            _Pragma("unroll")                                                 \
            for (int ii = 0; ii < 8; ii++)                                    \
                _Pragma("unroll")                                             \
                for (int jj = 0; jj < 8; jj++)                                \
                    acc[ii][jj] = fmaf(av[ii], wv[jj], acc[ii][jj]);          \
        }                                                                     \
    }

__global__ __launch_bounds__(64) void gemm64(const f4* __restrict__ in4,
                                             const float* __restrict__ W,
                                             const float* __restrict__ bias,
                                             f4* __restrict__ out4, int n) {
    __shared__ float At[64 * 64];
    __shared__ float Wt[64 * 64];
    int lane = threadIdx.x;
    int nb = blockIdx.x * 64;
    stage_T(Wt, (const f4*)W, lane, 64);
    stage_T(At, in4 + (size_t)nb * 16, lane, n - nb);
    __syncthreads();
    int r = lane & 7, c = lane >> 3;
    float acc[8][8];
#pragma unroll
    for (int ii = 0; ii < 8; ii++)
#pragma unroll
        for (int jj = 0; jj < 8; jj++) acc[ii][jj] = 0.f;
    GEMM_CORE(At, Wt, acc, r, c)
    float bq[8] = {0, 0, 0, 0, 0, 0, 0, 0};
    if (bias) {
        f4 b0 = ((const f4*)bias)[c * 2];
        f4 b1 = ((const f4*)bias)[c * 2 + 1];
        bq[0] = b0.x; bq[1] = b0.y; bq[2] = b0.z; bq[3] = b0.w;
        bq[4] = b1.x; bq[5] = b1.y; bq[6] = b1.z; bq[7] = b1.w;
    }
#pragma unroll
    for (int ii = 0; ii < 8; ii++) {
        int node = nb + r * 8 + ii;
        if (node < n) {
            out4[(size_t)node * 16 + c * 2] =
                make_float4(acc[ii][0] + bq[0], acc[ii][1] + bq[1],
                            acc[ii][2] + bq[2], acc[ii][3] + bq[3]);
            out4[(size_t)node * 16 + c * 2 + 1] =
                make_float4(acc[ii][4] + bq[4], acc[ii][5] + bq[5],
                            acc[ii][6] + bq[6], acc[ii][7] + bq[7]);
        }
    }
}

// GAT transform: ht = h@W.T plus per-node dots as = ht.a_src, ad = ht.a_dst
__global__ __launch_bounds__(64) void gat_gemm(const f4* __restrict__ in4,
                                               const float* __restrict__ W,
                                               const float* __restrict__ a_src,
                                               const float* __restrict__ a_dst,
                                               f4* __restrict__ ht4,
                                               float* __restrict__ as_,
                                               float* __restrict__ ad_, int n) {
    __shared__ float At[64 * 64];
    __shared__ float Wt[64 * 64];
    int lane = threadIdx.x;
    int nb = blockIdx.x * 64;
    stage_T(Wt, (const f4*)W, lane, 64);
    stage_T(At, in4 + (size_t)nb * 16, lane, n - nb);
    __syncthreads();
    int r = lane & 7, c = lane >> 3;
    float acc[8][8];
#pragma unroll
    for (int ii = 0; ii < 8; ii++)
#pragma unroll
        for (int jj = 0; jj < 8; jj++) acc[ii][jj] = 0.f;
    GEMM_CORE(At, Wt, acc, r, c)
    // write ht
#pragma unroll
    for (int ii = 0; ii < 8; ii++) {
        int node = nb + r * 8 + ii;
        if (node < n) {
            ht4[(size_t)node * 16 + c * 2] =
                make_float4(acc[ii][0], acc[ii][1], acc[ii][2], acc[ii][3]);
            ht4[(size_t)node * 16 + c * 2 + 1] =
                make_float4(acc[ii][4], acc[ii][5], acc[ii][6], acc[ii][7]);
        }
    }
    // attention dots
    f4 s0 = ((const f4*)a_src)[c * 2], s1 = ((const f4*)a_src)[c * 2 + 1];
    f4 d0 = ((const f4*)a_dst)[c * 2], d1 = ((const f4*)a_dst)[c * 2 + 1];
    float sv[8] = {s0.x, s0.y, s0.z, s0.w, s1.x, s1.y, s1.z, s1.w};
    float dv[8] = {d0.x, d0.y, d0.z, d0.w, d1.x, d1.y, d1.z, d1.w};
#pragma unroll
    for (int ii = 0; ii < 8; ii++) {
        float sd = 0.f, dd = 0.f;
#pragma unroll
        for (int jj = 0; jj < 8; jj++) {
            sd = fmaf(acc[ii][jj], sv[jj], sd);
            dd = fmaf(acc[ii][jj], dv[jj], dd);
        }
#pragma unroll
        for (int off = 8; off < 64; off <<= 1) {
            sd += __shfl_xor(sd, off);
            dd += __shfl_xor(dd, off);
        }
        int node = nb + r * 8 + ii;
        if (node < n) {
            if (c == 0) as_[node] = sd;
            if (c == 1) ad_[node] = dd;
        }
    }
}

// ---------------- SAGE gather: out = relu(mean_j Yl[j] + Zr[i]) ----------------

__global__ __launch_bounds__(256) void sage_gather(const f4* __restrict__ Yl,
                                                   const f4* __restrict__ Zr,
                                                   const int* __restrict__ rowptr,
                                                   const int* __restrict__ col,
                                                   f4* __restrict__ out,
                                                   int relu_flag, int n) {
    int t = blockIdx.x * 256 + threadIdx.x;
    int l16 = t & 15;
    int gbase = (threadIdx.x & 63) & 48;
    int stride = (gridDim.x * 256) >> 4;
    for (int node = t >> 4; node < n; node += stride) {
        int start = rowptr[node], end = rowptr[node + 1];
        f4 a0 = {0, 0, 0, 0}, a1 = {0, 0, 0, 0}, a2 = {0, 0, 0, 0}, a3 = {0, 0, 0, 0};
        for (int base = start; base < end; base += 16) {
            int idx = base + l16;
            int s_l = (idx < end) ? col[idx] : 0;
            int cnt = min(16, end - base);
            int i = 0;
            for (; i + 7 < cnt; i += 8) {
                int s0 = __shfl(s_l, gbase + i);
                int s1 = __shfl(s_l, gbase + i + 1);
                int s2 = __shfl(s_l, gbase + i + 2);
                int s3 = __shfl(s_l, gbase + i + 3);
                int s4 = __shfl(s_l, gbase + i + 4);
                int s5 = __shfl(s_l, gbase + i + 5);
                int s6 = __shfl(s_l, gbase + i + 6);
                int s7 = __shfl(s_l, gbase + i + 7);
                f4 r0 = Yl[(size_t)s0 * D4 + l16];
                f4 r1 = Yl[(size_t)s1 * D4 + l16];
                f4 r2 = Yl[(size_t)s2 * D4 + l16];
                f4 r3 = Yl[(size_t)s3 * D4 + l16];
                f4 r4 = Yl[(size_t)s4 * D4 + l16];
                f4 r5 = Yl[(size_t)s5 * D4 + l16];
                f4 r6 = Yl[(size_t)s6 * D4 + l16];
                f4 r7 = Yl[(size_t)s7 * D4 + l16];
                a0 = f4add(a0, r0); a1 = f4add(a1, r1);
                a2 = f4add(a2, r2); a3 = f4add(a3, r3);
                a0 = f4add(a0, r4); a1 = f4add(a1, r5);
                a2 = f4add(a2, r6); a3 = f4add(a3, r7);
            }
            for (; i < cnt; i++) {
                int s = __shfl(s_l, gbase + i);
                a0 = f4add(a0, Yl[(size_t)s * D4 + l16]);
            }
        }
        f4 a = f4add(f4add(a0, a1), f4add(a2, a3));
        float invd = 1.f / fmaxf((float)(end - start), 1.f);
        f4 z = Zr[(size_t)node * D4 + l16];
        f4 o = make_float4(fmaf(a.x, invd, z.x), fmaf(a.y, invd, z.y),
                           fmaf(a.z, invd, z.z), fmaf(a.w, invd, z.w));
        if (relu_flag) {
            o.x = fmaxf(o.x, 0.f); o.y = fmaxf(o.y, 0.f);
            o.z = fmaxf(o.z, 0.f); o.w = fmaxf(o.w, 0.f);
        }
        out[(size_t)node * D4 + l16] = o;
    }
}

// ---------------- GAT gather: single-pass online softmax + weighted agg ----------------

__global__ __launch_bounds__(256) void gat_gather(const int* __restrict__ rowptr,
                                                  const int* __restrict__ col,
                                                  const float* __restrict__ as_,
                                                  const float* __restrict__ ad_,
                                                  const f4* __restrict__ ht,
                                                  const float* __restrict__ b,
                                                  f4* __restrict__ out,
                                                  int relu_flag, int n) {
    int t = blockIdx.x * 256 + threadIdx.x;
    int l16 = t & 15;
    int gbase = (threadIdx.x & 63) & 48;
    int stride = (gridDim.x * 256) >> 4;
    const f4* b4 = (const f4*)b;
    for (int node = t >> 4; node < n; node += stride) {
        int start = rowptr[node], end = rowptr[node + 1];
        float ad_n = ad_[node];
        float e_self = leaky02(as_[node] + ad_n);
        float m = e_self;
        float z0 = 1.f, z1 = 0.f, z2 = 0.f, z3 = 0.f;
        f4 acc0 = ht[(size_t)node * D4 + l16];
        f4 acc1 = {0, 0, 0, 0}, acc2 = {0, 0, 0, 0}, acc3 = {0, 0, 0, 0};
        for (int base = start; base < end; base += 16) {
            int idx = base + l16;
            int cnt = min(16, end - base);
            int s_l = (idx < end) ? col[idx] : 0;
            float e_l = (idx < end) ? leaky02(as_[s_l] + ad_n) : -3.4e38f;
            float cm = e_l;
#pragma unroll
            for (int off = 8; off > 0; off >>= 1)
                cm = fmaxf(cm, __shfl_xor(cm, off));
            if (cm > m) {
                float sc = __expf(m - cm);
                z0 *= sc; z1 *= sc; z2 *= sc; z3 *= sc;
                acc0 = f4scale(acc0, sc); acc1 = f4scale(acc1, sc);
                acc2 = f4scale(acc2, sc); acc3 = f4scale(acc3, sc);
                m = cm;
            }
            float p_l = (idx < end) ? __expf(e_l - m) : 0.f;
            int i = 0;
            for (; i + 3 < cnt; i += 4) {
                int s0 = __shfl(s_l, gbase + i);
                int s1 = __shfl(s_l, gbase + i + 1);
                int s2 = __shfl(s_l, gbase + i + 2);
                int s3 = __shfl(s_l, gbase + i + 3);
                float p0 = __shfl(p_l, gbase + i);
                float p1 = __shfl(p_l, gbase + i + 1);
                float p2 = __shfl(p_l, gbase + i + 2);
                float p3 = __shfl(p_l, gbase + i + 3);
                f4 r0 = ht[(size_t)s0 * D4 + l16];
                f4 r1 = ht[(size_t)s1 * D4 + l16];
                f4 r2 = ht[(size_t)s2 * D4 + l16];
                f4 r3 = ht[(size_t)s3 * D4 + l16];
                z0 += p0; z1 += p1; z2 += p2; z3 += p3;
                acc0 = f4fma(p0, r0, acc0);
                acc1 = f4fma(p1, r1, acc1);
                acc2 = f4fma(p2, r2, acc2);
                acc3 = f4fma(p3, r3, acc3);
            }
            for (; i < cnt; i++) {
                int s0 = __shfl(s_l, gbase + i);
                float p0 = __shfl(p_l, gbase + i);
                z0 += p0;
                acc0 = f4fma(p0, ht[(size_t)s0 * D4 + l16], acc0);
            }
        }
        float rz = 1.f / ((z0 + z1) + (z2 + z3));
        f4 acc = f4add(f4add(acc0, acc1), f4add(acc2, acc3));
        f4 bb = b4[l16];
        f4 o = make_float4(fmaf(acc.x, rz, bb.x), fmaf(acc.y, rz, bb.y),
                           fmaf(acc.z, rz, bb.z), fmaf(acc.w, rz, bb.w));
        if (relu_flag) {
            o.x = fmaxf(o.x, 0.f); o.y = fmaxf(o.y, 0.f);
            o.z = fmaxf(o.z, 0.f); o.w = fmaxf(o.w, 0.f);
        }
        out[(size_t)node * D4 + l16] = o;
    }
}

// ---------------- MLP: one thread per node, scalar-loaded weights, fused layers ----------------

__global__ __launch_bounds__(256) void mlp_kernel(const float* __restrict__ h,
                                                  const float* __restrict__ W1,
                                                  const float* __restrict__ b1,
                                                  const float* __restrict__ W2,
                                                  const float* __restrict__ b2,
                                                  const float* __restrict__ W3,
                                                  const float* __restrict__ b3,
                                                  float* __restrict__ out, int n) {
    int node = blockIdx.x * 256 + threadIdx.x;
    if (node >= n) return;
    float hreg[64];
    const f4* hp = (const f4*)(h + (size_t)node * D);
#pragma unroll
    for (int i = 0; i < 16; i++) {
        f4 r = hp[i];
        hreg[4 * i] = r.x; hreg[4 * i + 1] = r.y;
        hreg[4 * i + 2] = r.z; hreg[4 * i + 3] = r.w;
    }
    float v2[32];
#pragma unroll
    for (int o = 0; o < 32; o++) v2[o] = b2[o];
    for (int og = 0; og < 16; og++) {
        const float* w = W1 + og * 4 * 64;
        float a0 = b1[og * 4], a1 = b1[og * 4 + 1];
        float a2 = b1[og * 4 + 2], a3 = b1[og * 4 + 3];
#pragma unroll
        for (int k = 0; k < 64; k++) {
            float hk = hreg[k];
            a0 = fmaf(hk, w[k], a0);
            a1 = fmaf(hk, w[64 + k], a1);
            a2 = fmaf(hk, w[128 + k], a2);
            a3 = fmaf(hk, w[192 + k], a3);
        }
        a0 = fmaxf(a0, 0.f); a1 = fmaxf(a1, 0.f);
        a2 = fmaxf(a2, 0.f); a3 = fmaxf(a3, 0.f);
        const float* w2c = W2 + og * 4;
#pragma unroll
        for (int o = 0; o < 32; o++) {
            v2[o] = fmaf(a0, w2c[o * 64], v2[o]);
            v2[o] = fmaf(a1, w2c[o * 64 + 1], v2[o]);
            v2[o] = fmaf(a2, w2c[o * 64 + 2], v2[o]);
            v2[o] = fmaf(a3, w2c[o * 64 + 3], v2[o]);
        }
    }
#pragma unroll
    for (int o = 0; o < 32; o++) v2[o] = fmaxf(v2[o], 0.f);
    f4* op = (f4*)(out + (size_t)node * 16);
    for (int og = 0; og < 4; og++) {
        const float* w = W3 + og * 4 * 32;
        float a0 = b3[og * 4], a1 = b3[og * 4 + 1];
        float a2 = b3[og * 4 + 2], a3 = b3[og * 4 + 3];
#pragma unroll
        for (int k = 0; k < 32; k++) {
            float vk = v2[k];
            a0 = fmaf(vk, w[k], a0);
            a1 = fmaf(vk, w[32 + k], a1);
            a2 = fmaf(vk, w[64 + k], a2);
            a3 = fmaf(vk, w[96 + k], a3);
        }
        op[og] = make_float4(a0, a1, a2, a3);
    }
}

// ---------------- launch ----------------

extern "C" void kernel_launch(void* const* d_in, const int* in_sizes, int n_in,
                              void* d_out, int out_size, void* d_ws, size_t ws_size,
                              hipStream_t stream) {
    const int n  = in_sizes[0] / D;      // 100000
    const int ne = in_sizes[1] / 2;      // 1600000

    const float* x        = (const float*)d_in[0];
    const int*   ei       = (const int*)d_in[1];
    const int*   src      = ei;
    const int*   dst      = ei + ne;
    const float* sage_Wl  = (const float*)d_in[2];
    const float* sage_bl  = (const float*)d_in[3];
    const float* sage_Wr  = (const float*)d_in[4];
    const float* gat_W    = (const float*)d_in[5];
    const float* gat_asrc = (const float*)d_in[6];
    const float* gat_adst = (const float*)d_in[7];
    const float* gat_b    = (const float*)d_in[8];
    const float* W1 = (const float*)d_in[9];
    const float* b1 = (const float*)d_in[10];
    const float* W2 = (const float*)d_in[11];
    const float* b2 = (const float*)d_in[12];
    const float* W3 = (const float*)d_in[13];
    const float* b3 = (const float*)d_in[14];
    float* out = (float*)d_out;

    // workspace layout (4B units, all offsets 16B-aligned)
    int*   cnt      = (int*)d_ws;                    // n
    int*   incl     = cnt + n;                       // n
    int*   rowptr   = incl + n;                      // n+4
    int*   cursor   = rowptr + n + 4;                // n
    int*   partials = cursor + n;                    // 1024
    int*   col      = partials + 1024;               // ne
    float* as_      = (float*)(col + ne);            // n
    float* ad_      = as_ + n;                       // n
    float* Yl       = ad_ + n;                       // n*D (also GAT ht)
    float* Zr       = Yl + (size_t)n * D;            // n*D
    float* bufA     = Zr + (size_t)n * D;            // n*D
    float* bufB     = bufA + (size_t)n * D;          // n*D

    const int gridE  = (ne + 255) / 256;
    const int nb     = (n + SCAN_BS - 1) / SCAN_BS;
    const int gridG  = (n * 16 + 255) / 256;         // 16 lanes per node
    const int gridM  = (n + 63) / 64;                // 64-node GEMM tiles
    const int gridT  = (n + 255) / 256;

    // ---- CSR build ----
    hipMemsetAsync(cnt, 0, (size_t)n * 4, stream);
    hist_kernel<<<gridE, 256, 0, stream>>>(dst, cnt, ne);
    scan1_kernel<<<nb, SCAN_BS, 0, stream>>>(cnt, incl, partials, n);
    scan2_kernel<<<1, 1024, 0, stream>>>(partials, nb);
    scan3_kernel<<<nb, SCAN_BS, 0, stream>>>(cnt, incl, partials, rowptr, cursor, n, ne);
    fill_kernel<<<gridE, 256, 0, stream>>>(src, dst, cursor, col, ne);

    // ---- 4 SAGE layers (x -> A -> B -> A -> B) ----
    const float* cur = x;
    float* nxt = bufA;
    for (int l = 0; l < 4; l++) {
        gemm64<<<gridM, 64, 0, stream>>>((const f4*)cur,
                                         sage_Wl + (size_t)l * D * D, nullptr,
                                         (f4*)Yl, n);
        gemm64<<<gridM, 64, 0, stream>>>((const f4*)cur,
                                         sage_Wr + (size_t)l * D * D,
                                         sage_bl + (size_t)l * D,
                                         (f4*)Zr, n);
        sage_gather<<<gridG, 256, 0, stream>>>((const f4*)Yl, (const f4*)Zr,
                                               rowptr, col, (f4*)nxt,
                                               (l < 3) ? 1 : 0, n);
        cur = nxt;
        nxt = (nxt == bufA) ? bufB : bufA;
    }
    // cur == bufB

    // ---- 4 GAT layers (in-place on bufB, ht reuses Yl) ----
    float* gin = bufB;
    for (int l = 0; l < 4; l++) {
        gat_gemm<<<gridM, 64, 0, stream>>>((const f4*)gin,
                                           gat_W + (size_t)l * D * D,
                                           gat_asrc + (size_t)l * D,
                                           gat_adst + (size_t)l * D,
                                           (f4*)Yl, as_, ad_, n);
        gat_gather<<<gridG, 256, 0, stream>>>(rowptr, col, as_, ad_,
                                              (const f4*)Yl,
                                              gat_b + (size_t)l * D, (f4*)gin,
                                              (l < 3) ? 1 : 0, n);
    }

    // ---- projection MLP ----
    mlp_kernel<<<gridT, 256, 0, stream>>>(gin, W1, b1, W2, b2, W3, b3, out, n);
}

// Round 7
// 1610.780 us; speedup vs baseline: 4.1323x; 4.1323x over previous
//
#include <hip/hip_runtime.h>

#define D 64
#define D4 16   // D/4 float4 per row

typedef float4 f4;

__device__ __forceinline__ float leaky02(float x) { return (x >= 0.f) ? x : 0.2f * x; }

__device__ __forceinline__ f4 f4add(f4 a, f4 b) {
    return make_float4(a.x + b.x, a.y + b.y, a.z + b.z, a.w + b.w);
}
__device__ __forceinline__ f4 f4fma(float s, f4 v, f4 a) {
    return make_float4(fmaf(s, v.x, a.x), fmaf(s, v.y, a.y), fmaf(s, v.z, a.z), fmaf(s, v.w, a.w));
}
__device__ __forceinline__ f4 f4scale(f4 a, float s) {
    return make_float4(a.x * s, a.y * s, a.z * s, a.w * s);
}

// ---------------- CSR build ----------------

__global__ __launch_bounds__(256) void hist_kernel(const int* __restrict__ dst,
                                                   int* __restrict__ cnt, int ne) {
    int e = blockIdx.x * blockDim.x + threadIdx.x;
    if (e < ne) atomicAdd(&cnt[dst[e]], 1);
}

#define SCAN_BS 256
__global__ __launch_bounds__(SCAN_BS) void scan1_kernel(const int* __restrict__ cnt,
                                                        int* __restrict__ incl,
                                                        int* __restrict__ partials, int n) {
    __shared__ int sm[SCAN_BS];
    int g = blockIdx.x * SCAN_BS + threadIdx.x;
    int v = (g < n) ? cnt[g] : 0;
    sm[threadIdx.x] = v;
    __syncthreads();
    for (int off = 1; off < SCAN_BS; off <<= 1) {
        int t = (threadIdx.x >= off) ? sm[threadIdx.x - off] : 0;
        __syncthreads();
        sm[threadIdx.x] += t;
        __syncthreads();
    }
    if (g < n) incl[g] = sm[threadIdx.x];
    if (threadIdx.x == SCAN_BS - 1) partials[blockIdx.x] = sm[threadIdx.x];
}

__global__ __launch_bounds__(1024) void scan2_kernel(int* __restrict__ partials, int nb) {
    __shared__ int sm[1024];
    int t = threadIdx.x;
    int v = (t < nb) ? partials[t] : 0;
    sm[t] = v;
    __syncthreads();
    for (int off = 1; off < 1024; off <<= 1) {
        int x = (t >= off) ? sm[t - off] : 0;
        __syncthreads();
        sm[t] += x;
        __syncthreads();
    }
    if (t < nb) partials[t] = sm[t] - v;   // exclusive
}

__global__ __launch_bounds__(SCAN_BS) void scan3_kernel(const int* __restrict__ cnt,
                                                        const int* __restrict__ incl,
                                                        const int* __restrict__ partials,
                                                        int* __restrict__ rowptr,
                                                        int* __restrict__ cursor, int n, int ne) {
    int g = blockIdx.x * SCAN_BS + threadIdx.x;
    if (g < n) {
        int rp = incl[g] - cnt[g] + partials[blockIdx.x];
        rowptr[g] = rp;
        cursor[g] = rp;
    }
    if (g == 0) rowptr[n] = ne;
}

__global__ __launch_bounds__(256) void fill_kernel(const int* __restrict__ src,
                                                   const int* __restrict__ dst,
                                                   int* __restrict__ cursor,
                                                   int* __restrict__ col, int ne) {
    int e = blockIdx.x * blockDim.x + threadIdx.x;
    if (e < ne) {
        int pos = atomicAdd(&cursor[dst[e]], 1);
        col[pos] = src[e];
    }
}

// ---------------- SAGE dense: Yl = h@Wl.T ; Zr = h@Wr.T + bl ----------------
// One thread per node; weights via wave-uniform (scalar) loads.
// Output stores batched per 64B line group -> full-line HBM writes.

__global__ __launch_bounds__(256) void sage_dense(const float* __restrict__ h,
                                                  const float* __restrict__ Wl,
                                                  const float* __restrict__ bl,
                                                  const float* __restrict__ Wr,
                                                  float* __restrict__ Yl,
                                                  float* __restrict__ Zr, int n) {
    int node = blockIdx.x * 256 + threadIdx.x;
    if (node >= n) return;
    float hreg[64];
    const f4* hp = (const f4*)(h + (size_t)node * D);
#pragma unroll
    for (int i = 0; i < 16; i++) {
        f4 r = hp[i];
        hreg[4 * i] = r.x; hreg[4 * i + 1] = r.y;
        hreg[4 * i + 2] = r.z; hreg[4 * i + 3] = r.w;
    }
    f4* yp = (f4*)(Yl + (size_t)node * D);
    f4* zp = (f4*)(Zr + (size_t)node * D);
    // Y pass: 4 line groups of 16 outputs, stores back-to-back per group
    for (int lg = 0; lg < 4; lg++) {
        f4 ov[4];
#pragma unroll
        for (int og = 0; og < 4; og++) {
            const float* w = Wl + (lg * 4 + og) * 4 * D;
            float a0 = 0.f, a1 = 0.f, a2 = 0.f, a3 = 0.f;
#pragma unroll
            for (int k = 0; k < 64; k++) {
                float hk = hreg[k];
                a0 = fmaf(hk, w[k], a0);
                a1 = fmaf(hk, w[64 + k], a1);
                a2 = fmaf(hk, w[128 + k], a2);
                a3 = fmaf(hk, w[192 + k], a3);
            }
            ov[og] = make_float4(a0, a1, a2, a3);
        }
        yp[lg * 4 + 0] = ov[0];
        yp[lg * 4 + 1] = ov[1];
        yp[lg * 4 + 2] = ov[2];
        yp[lg * 4 + 3] = ov[3];
    }
    // Z pass
    for (int lg = 0; lg < 4; lg++) {
        f4 ov[4];
#pragma unroll
        for (int og = 0; og < 4; og++) {
            int o = (lg * 4 + og) * 4;
            const float* w = Wr + o * D;
            float a0 = bl[o], a1 = bl[o + 1], a2 = bl[o + 2], a3 = bl[o + 3];
#pragma unroll
            for (int k = 0; k < 64; k++) {
                float hk = hreg[k];
                a0 = fmaf(hk, w[k], a0);
                a1 = fmaf(hk, w[64 + k], a1);
                a2 = fmaf(hk, w[128 + k], a2);
                a3 = fmaf(hk, w[192 + k], a3);
            }
            ov[og] = make_float4(a0, a1, a2, a3);
        }
        zp[lg * 4 + 0] = ov[0];
        zp[lg * 4 + 1] = ov[1];
        zp[lg * 4 + 2] = ov[2];
        zp[lg * 4 + 3] = ov[3];
    }
}

// ---------------- SAGE gather: out = relu(mean_j Yl[j] + Zr[i]) ----------------

__global__ __launch_bounds__(256) void sage_gather(const f4* __restrict__ Yl,
                                                   const f4* __restrict__ Zr,
                                                   const int* __restrict__ rowptr,
                                                   const int* __restrict__ col,
                                                   f4* __restrict__ out,
                                                   int relu_flag, int n) {
    int t = blockIdx.x * 256 + threadIdx.x;
    int l16 = t & 15;
    int gbase = (threadIdx.x & 63) & 48;
    int stride = (gridDim.x * 256) >> 4;
    for (int node = t >> 4; node < n; node += stride) {
        int start = rowptr[node], end = rowptr[node + 1];
        f4 a0 = {0, 0, 0, 0}, a1 = {0, 0, 0, 0}, a2 = {0, 0, 0, 0}, a3 = {0, 0, 0, 0};
        for (int base = start; base < end; base += 16) {
            int idx = base + l16;
            int s_l = (idx < end) ? col[idx] : 0;
            int cnt = min(16, end - base);
            int i = 0;
            for (; i + 7 < cnt; i += 8) {
                int s0 = __shfl(s_l, gbase + i);
                int s1 = __shfl(s_l, gbase + i + 1);
                int s2 = __shfl(s_l, gbase + i + 2);
                int s3 = __shfl(s_l, gbase + i + 3);
                int s4 = __shfl(s_l, gbase + i + 4);
                int s5 = __shfl(s_l, gbase + i + 5);
                int s6 = __shfl(s_l, gbase + i + 6);
                int s7 = __shfl(s_l, gbase + i + 7);
                f4 r0 = Yl[(size_t)s0 * D4 + l16];
                f4 r1 = Yl[(size_t)s1 * D4 + l16];
                f4 r2 = Yl[(size_t)s2 * D4 + l16];
                f4 r3 = Yl[(size_t)s3 * D4 + l16];
                f4 r4 = Yl[(size_t)s4 * D4 + l16];
                f4 r5 = Yl[(size_t)s5 * D4 + l16];
                f4 r6 = Yl[(size_t)s6 * D4 + l16];
                f4 r7 = Yl[(size_t)s7 * D4 + l16];
                a0 = f4add(a0, r0); a1 = f4add(a1, r1);
                a2 = f4add(a2, r2); a3 = f4add(a3, r3);
                a0 = f4add(a0, r4); a1 = f4add(a1, r5);
                a2 = f4add(a2, r6); a3 = f4add(a3, r7);
            }
            for (; i < cnt; i++) {
                int s = __shfl(s_l, gbase + i);
                a0 = f4add(a0, Yl[(size_t)s * D4 + l16]);
            }
        }
        f4 a = f4add(f4add(a0, a1), f4add(a2, a3));
        float invd = 1.f / fmaxf((float)(end - start), 1.f);
        f4 z = Zr[(size_t)node * D4 + l16];
        f4 o = make_float4(fmaf(a.x, invd, z.x), fmaf(a.y, invd, z.y),
                           fmaf(a.z, invd, z.z), fmaf(a.w, invd, z.w));
        if (relu_flag) {
            o.x = fmaxf(o.x, 0.f); o.y = fmaxf(o.y, 0.f);
            o.z = fmaxf(o.z, 0.f); o.w = fmaxf(o.w, 0.f);
        }
        out[(size_t)node * D4 + l16] = o;
    }
}

// ---------------- GAT dense: ht = h@W.T ; as = ht.a_src ; ad = ht.a_dst ----------------
// One thread per node; scalar weight loads; line-batched stores.

__global__ __launch_bounds__(256) void gat_transform(const float* __restrict__ h,
                                                     const float* __restrict__ W,
                                                     const float* __restrict__ a_src,
                                                     const float* __restrict__ a_dst,
                                                     float* __restrict__ ht,
                                                     float* __restrict__ as_,
                                                     float* __restrict__ ad_, int n) {
    int node = blockIdx.x * 256 + threadIdx.x;
    if (node >= n) return;
    float hreg[64];
    const f4* hp = (const f4*)(h + (size_t)node * D);
#pragma unroll
    for (int i = 0; i < 16; i++) {
        f4 r = hp[i];
        hreg[4 * i] = r.x; hreg[4 * i + 1] = r.y;
        hreg[4 * i + 2] = r.z; hreg[4 * i + 3] = r.w;
    }
    f4* hto = (f4*)(ht + (size_t)node * D);
    float s_acc = 0.f, d_acc = 0.f;
    for (int lg = 0; lg < 4; lg++) {
        f4 ov[4];
#pragma unroll
        for (int og = 0; og < 4; og++) {
            int o = (lg * 4 + og) * 4;
            const float* w = W + o * D;
            float a0 = 0.f, a1 = 0.f, a2 = 0.f, a3 = 0.f;
#pragma unroll
            for (int k = 0; k < 64; k++) {
                float hk = hreg[k];
                a0 = fmaf(hk, w[k], a0);
                a1 = fmaf(hk, w[64 + k], a1);
                a2 = fmaf(hk, w[128 + k], a2);
                a3 = fmaf(hk, w[192 + k], a3);
            }
            ov[og] = make_float4(a0, a1, a2, a3);
            s_acc = fmaf(a0, a_src[o], s_acc);
            s_acc = fmaf(a1, a_src[o + 1], s_acc);
            s_acc = fmaf(a2, a_src[o + 2], s_acc);
            s_acc = fmaf(a3, a_src[o + 3], s_acc);
            d_acc = fmaf(a0, a_dst[o], d_acc);
            d_acc = fmaf(a1, a_dst[o + 1], d_acc);
            d_acc = fmaf(a2, a_dst[o + 2], d_acc);
            d_acc = fmaf(a3, a_dst[o + 3], d_acc);
        }
        hto[lg * 4 + 0] = ov[0];
        hto[lg * 4 + 1] = ov[1];
        hto[lg * 4 + 2] = ov[2];
        hto[lg * 4 + 3] = ov[3];
    }
    as_[node] = s_acc;
    ad_[node] = d_acc;
}

// ---------------- GAT gather: single-pass online softmax + weighted agg ----------------

__global__ __launch_bounds__(256) void gat_gather(const int* __restrict__ rowptr,
                                                  const int* __restrict__ col,
                                                  const float* __restrict__ as_,
                                                  const float* __restrict__ ad_,
                                                  const f4* __restrict__ ht,
                                                  const float* __restrict__ b,
                                                  f4* __restrict__ out,
                                                  int relu_flag, int n) {
    int t = blockIdx.x * 256 + threadIdx.x;
    int l16 = t & 15;
    int gbase = (threadIdx.x & 63) & 48;
    int stride = (gridDim.x * 256) >> 4;
    const f4* b4 = (const f4*)b;
    for (int node = t >> 4; node < n; node += stride) {
        int start = rowptr[node], end = rowptr[node + 1];
        float ad_n = ad_[node];
        float e_self = leaky02(as_[node] + ad_n);
        float m = e_self;
        float z0 = 1.f, z1 = 0.f, z2 = 0.f, z3 = 0.f;
        f4 acc0 = ht[(size_t)node * D4 + l16];
        f4 acc1 = {0, 0, 0, 0}, acc2 = {0, 0, 0, 0}, acc3 = {0, 0, 0, 0};
        for (int base = start; base < end; base += 16) {
            int idx = base + l16;
            int cnt = min(16, end - base);
            int s_l = (idx < end) ? col[idx] : 0;
            float e_l = (idx < end) ? leaky02(as_[s_l] + ad_n) : -3.4e38f;
            float cm = e_l;
#pragma unroll
            for (int off = 8; off > 0; off >>= 1)
                cm = fmaxf(cm, __shfl_xor(cm, off));
            if (cm > m) {
                float sc = __expf(m - cm);
                z0 *= sc; z1 *= sc; z2 *= sc; z3 *= sc;
                acc0 = f4scale(acc0, sc); acc1 = f4scale(acc1, sc);
                acc2 = f4scale(acc2, sc); acc3 = f4scale(acc3, sc);
                m = cm;
            }
            float p_l = (idx < end) ? __expf(e_l - m) : 0.f;
            int i = 0;
            for (; i + 3 < cnt; i += 4) {
                int s0 = __shfl(s_l, gbase + i);
                int s1 = __shfl(s_l, gbase + i + 1);
                int s2 = __shfl(s_l, gbase + i + 2);
                int s3 = __shfl(s_l, gbase + i + 3);
                float p0 = __shfl(p_l, gbase + i);
                float p1 = __shfl(p_l, gbase + i + 1);
                float p2 = __shfl(p_l, gbase + i + 2);
                float p3 = __shfl(p_l, gbase + i + 3);
                f4 r0 = ht[(size_t)s0 * D4 + l16];
                f4 r1 = ht[(size_t)s1 * D4 + l16];
                f4 r2 = ht[(size_t)s2 * D4 + l16];
                f4 r3 = ht[(size_t)s3 * D4 + l16];
                z0 += p0; z1 += p1; z2 += p2; z3 += p3;
                acc0 = f4fma(p0, r0, acc0);
                acc1 = f4fma(p1, r1, acc1);
                acc2 = f4fma(p2, r2, acc2);
                acc3 = f4fma(p3, r3, acc3);
            }
            for (; i < cnt; i++) {
                int s0 = __shfl(s_l, gbase + i);
                float p0 = __shfl(p_l, gbase + i);
                z0 += p0;
                acc0 = f4fma(p0, ht[(size_t)s0 * D4 + l16], acc0);
            }
        }
        float rz = 1.f / ((z0 + z1) + (z2 + z3));
        f4 acc = f4add(f4add(acc0, acc1), f4add(acc2, acc3));
        f4 bb = b4[l16];
        f4 o = make_float4(fmaf(acc.x, rz, bb.x), fmaf(acc.y, rz, bb.y),
                           fmaf(acc.z, rz, bb.z), fmaf(acc.w, rz, bb.w));
        if (relu_flag) {
            o.x = fmaxf(o.x, 0.f); o.y = fmaxf(o.y, 0.f);
            o.z = fmaxf(o.z, 0.f); o.w = fmaxf(o.w, 0.f);
        }
        out[(size_t)node * D4 + l16] = o;
    }
}

// ---------------- MLP: one thread per node, scalar-loaded weights, fused layers ----------------

__global__ __launch_bounds__(256) void mlp_kernel(const float* __restrict__ h,
                                                  const float* __restrict__ W1,
                                                  const float* __restrict__ b1,
                                                  const float* __restrict__ W2,
                                                  const float* __restrict__ b2,
                                                  const float* __restrict__ W3,
                                                  const float* __restrict__ b3,
                                                  float* __restrict__ out, int n) {
    int node = blockIdx.x * 256 + threadIdx.x;
    if (node >= n) return;
    float hreg[64];
    const f4* hp = (const f4*)(h + (size_t)node * D);
#pragma unroll
    for (int i = 0; i < 16; i++) {
        f4 r = hp[i];
        hreg[4 * i] = r.x; hreg[4 * i + 1] = r.y;
        hreg[4 * i + 2] = r.z; hreg[4 * i + 3] = r.w;
    }
    float v2[32];
#pragma unroll
    for (int o = 0; o < 32; o++) v2[o] = b2[o];
    for (int og = 0; og < 16; og++) {
        const float* w = W1 + og * 4 * 64;
        float a0 = b1[og * 4], a1 = b1[og * 4 + 1];
        float a2 = b1[og * 4 + 2], a3 = b1[og * 4 + 3];
#pragma unroll
        for (int k = 0; k < 64; k++) {
            float hk = hreg[k];
            a0 = fmaf(hk, w[k], a0);
            a1 = fmaf(hk, w[64 + k], a1);
            a2 = fmaf(hk, w[128 + k], a2);
            a3 = fmaf(hk, w[192 + k], a3);
        }
        a0 = fmaxf(a0, 0.f); a1 = fmaxf(a1, 0.f);
        a2 = fmaxf(a2, 0.f); a3 = fmaxf(a3, 0.f);
        const float* w2c = W2 + og * 4;
#pragma unroll
        for (int o = 0; o < 32; o++) {
            v2[o] = fmaf(a0, w2c[o * 64], v2[o]);
            v2[o] = fmaf(a1, w2c[o * 64 + 1], v2[o]);
            v2[o] = fmaf(a2, w2c[o * 64 + 2], v2[o]);
            v2[o] = fmaf(a3, w2c[o * 64 + 3], v2[o]);
        }
    }
#pragma unroll
    for (int o = 0; o < 32; o++) v2[o] = fmaxf(v2[o], 0.f);
    f4 ov[4];
    for (int og = 0; og < 4; og++) {
        const float* w = W3 + og * 4 * 32;
        float a0 = b3[og * 4], a1 = b3[og * 4 + 1];
        float a2 = b3[og * 4 + 2], a3 = b3[og * 4 + 3];
#pragma unroll
        for (int k = 0; k < 32; k++) {
            float vk = v2[k];
            a0 = fmaf(vk, w[k], a0);
            a1 = fmaf(vk, w[32 + k], a1);
            a2 = fmaf(vk, w[64 + k], a2);
            a3 = fmaf(vk, w[96 + k], a3);
        }
        ov[og] = make_float4(a0, a1, a2, a3);
    }
    f4* op = (f4*)(out + (size_t)node * 16);
    op[0] = ov[0]; op[1] = ov[1]; op[2] = ov[2]; op[3] = ov[3];
}

// ---------------- launch ----------------

extern "C" void kernel_launch(void* const* d_in, const int* in_sizes, int n_in,
                              void* d_out, int out_size, void* d_ws, size_t ws_size,
                              hipStream_t stream) {
    const int n  = in_sizes[0] / D;      // 100000
    const int ne = in_sizes[1] / 2;      // 1600000

    const float* x        = (const float*)d_in[0];
    const int*   ei       = (const int*)d_in[1];
    const int*   src      = ei;
    const int*   dst      = ei + ne;
    const float* sage_Wl  = (const float*)d_in[2];
    const float* sage_bl  = (const float*)d_in[3];
    const float* sage_Wr  = (const float*)d_in[4];
    const float* gat_W    = (const float*)d_in[5];
    const float* gat_asrc = (const float*)d_in[6];
    const float* gat_adst = (const float*)d_in[7];
    const float* gat_b    = (const float*)d_in[8];
    const float* W1 = (const float*)d_in[9];
    const float* b1 = (const float*)d_in[10];
    const float* W2 = (const float*)d_in[11];
    const float* b2 = (const float*)d_in[12];
    const float* W3 = (const float*)d_in[13];
    const float* b3 = (const float*)d_in[14];
    float* out = (float*)d_out;

    // workspace layout (4B units, all offsets 16B-aligned)
    int*   cnt      = (int*)d_ws;                    // n
    int*   incl     = cnt + n;                       // n
    int*   rowptr   = incl + n;                      // n+4
    int*   cursor   = rowptr + n + 4;                // n
    int*   partials = cursor + n;                    // 1024
    int*   col      = partials + 1024;               // ne
    float* as_      = (float*)(col + ne);            // n
    float* ad_      = as_ + n;                       // n
    float* Yl       = ad_ + n;                       // n*D (also GAT ht)
    float* Zr       = Yl + (size_t)n * D;            // n*D
    float* bufA     = Zr + (size_t)n * D;            // n*D
    float* bufB     = bufA + (size_t)n * D;          // n*D

    const int gridE  = (ne + 255) / 256;
    const int nb     = (n + SCAN_BS - 1) / SCAN_BS;
    const int gridG  = (n * 16 + 255) / 256;         // 16 lanes per node
    const int gridT  = (n + 255) / 256;              // 1 thread per node

    // ---- CSR build ----
    hipMemsetAsync(cnt, 0, (size_t)n * 4, stream);
    hist_kernel<<<gridE, 256, 0, stream>>>(dst, cnt, ne);
    scan1_kernel<<<nb, SCAN_BS, 0, stream>>>(cnt, incl, partials, n);
    scan2_kernel<<<1, 1024, 0, stream>>>(partials, nb);
    scan3_kernel<<<nb, SCAN_BS, 0, stream>>>(cnt, incl, partials, rowptr, cursor, n, ne);
    fill_kernel<<<gridE, 256, 0, stream>>>(src, dst, cursor, col, ne);

    // ---- 4 SAGE layers (x -> A -> B -> A -> B) ----
    const float* cur = x;
    float* nxt = bufA;
    for (int l = 0; l < 4; l++) {
        sage_dense<<<gridT, 256, 0, stream>>>(cur,
                                              sage_Wl + (size_t)l * D * D,
                                              sage_bl + (size_t)l * D,
                                              sage_Wr + (size_t)l * D * D,
                                              Yl, Zr, n);
        sage_gather<<<gridG, 256, 0, stream>>>((const f4*)Yl, (const f4*)Zr,
                                               rowptr, col, (f4*)nxt,
                                               (l < 3) ? 1 : 0, n);
        cur = nxt;
        nxt = (nxt == bufA) ? bufB : bufA;
    }
    // cur == bufB

    // ---- 4 GAT layers (in-place on bufB, ht reuses Yl) ----
    float* gin = bufB;
    for (int l = 0; l < 4; l++) {
        gat_transform<<<gridT, 256, 0, stream>>>(gin,
                                                 gat_W + (size_t)l * D * D,
                                                 gat_asrc + (size_t)l * D,
                                                 gat_adst + (size_t)l * D,
                                                 Yl, as_, ad_, n);
        gat_gather<<<gridG, 256, 0, stream>>>(rowptr, col, as_, ad_,
                                              (const f4*)Yl,
                                              gat_b + (size_t)l * D, (f4*)gin,
                                              (l < 3) ? 1 : 0, n);
    }

    // ---- projection MLP ----
    mlp_kernel<<<gridT, 256, 0, stream>>>(gin, W1, b1, W2, b2, W3, b3, out, n);
}

// Round 8
// 1108.845 us; speedup vs baseline: 6.0029x; 1.4527x over previous
//
#include <hip/hip_runtime.h>

#define D 64
#define D4 16   // D/4 float4 per row
#define PITCH 68  // LDS tile pitch: 16B-aligned b128 rows, <=2-way banks

typedef float4 f4;

__device__ __forceinline__ float leaky02(float x) { return (x >= 0.f) ? x : 0.2f * x; }

__device__ __forceinline__ f4 f4add(f4 a, f4 b) {
    return make_float4(a.x + b.x, a.y + b.y, a.z + b.z, a.w + b.w);
}
__device__ __forceinline__ f4 f4fma(float s, f4 v, f4 a) {
    return make_float4(fmaf(s, v.x, a.x), fmaf(s, v.y, a.y), fmaf(s, v.z, a.z), fmaf(s, v.w, a.w));
}
__device__ __forceinline__ f4 f4scale(f4 a, float s) {
    return make_float4(a.x * s, a.y * s, a.z * s, a.w * s);
}

// ---------------- CSR build ----------------

__global__ __launch_bounds__(256) void hist_kernel(const int* __restrict__ dst,
                                                   int* __restrict__ cnt, int ne) {
    int e = blockIdx.x * blockDim.x + threadIdx.x;
    if (e < ne) atomicAdd(&cnt[dst[e]], 1);
}

#define SCAN_BS 256
__global__ __launch_bounds__(SCAN_BS) void scan1_kernel(const int* __restrict__ cnt,
                                                        int* __restrict__ incl,
                                                        int* __restrict__ partials, int n) {
    __shared__ int sm[SCAN_BS];
    int g = blockIdx.x * SCAN_BS + threadIdx.x;
    int v = (g < n) ? cnt[g] : 0;
    sm[threadIdx.x] = v;
    __syncthreads();
    for (int off = 1; off < SCAN_BS; off <<= 1) {
        int t = (threadIdx.x >= off) ? sm[threadIdx.x - off] : 0;
        __syncthreads();
        sm[threadIdx.x] += t;
        __syncthreads();
    }
    if (g < n) incl[g] = sm[threadIdx.x];
    if (threadIdx.x == SCAN_BS - 1) partials[blockIdx.x] = sm[threadIdx.x];
}

__global__ __launch_bounds__(1024) void scan2_kernel(int* __restrict__ partials, int nb) {
    __shared__ int sm[1024];
    int t = threadIdx.x;
    int v = (t < nb) ? partials[t] : 0;
    sm[t] = v;
    __syncthreads();
    for (int off = 1; off < 1024; off <<= 1) {
        int x = (t >= off) ? sm[t - off] : 0;
        __syncthreads();
        sm[t] += x;
        __syncthreads();
    }
    if (t < nb) partials[t] = sm[t] - v;   // exclusive
}

__global__ __launch_bounds__(SCAN_BS) void scan3_kernel(const int* __restrict__ cnt,
                                                        const int* __restrict__ incl,
                                                        const int* __restrict__ partials,
                                                        int* __restrict__ rowptr,
                                                        int* __restrict__ cursor, int n, int ne) {
    int g = blockIdx.x * SCAN_BS + threadIdx.x;
    if (g < n) {
        int rp = incl[g] - cnt[g] + partials[blockIdx.x];
        rowptr[g] = rp;
        cursor[g] = rp;
    }
    if (g == 0) rowptr[n] = ne;
}

__global__ __launch_bounds__(256) void fill_kernel(const int* __restrict__ src,
                                                   const int* __restrict__ dst,
                                                   int* __restrict__ cursor,
                                                   int* __restrict__ col, int ne) {
    int e = blockIdx.x * blockDim.x + threadIdx.x;
    if (e < ne) {
        int pos = atomicAdd(&cursor[dst[e]], 1);
        col[pos] = src[e];
    }
}

// ---------------- LDS staging: T[k][row] transposed from row-major G[rows][64] ----------------
// t in [0,256): row = t>>2, kq = (t&3)+4c. Coalesced f4 loads; <=2-way bank writes.

__device__ __forceinline__ void stageT(float* __restrict__ T, const f4* __restrict__ G4,
                                       int t, int valid_rows) {
    int row = t >> 2;
    int kq0 = t & 3;
#pragma unroll
    for (int c = 0; c < 4; c++) {
        int kq = kq0 + 4 * c;
        f4 r = make_float4(0.f, 0.f, 0.f, 0.f);
        if (row < valid_rows) r = G4[(size_t)row * 16 + kq];
        int k0 = kq * 4;
        T[(k0 + 0) * PITCH + row] = r.x;
        T[(k0 + 1) * PITCH + row] = r.y;
        T[(k0 + 2) * PITCH + row] = r.z;
        T[(k0 + 3) * PITCH + row] = r.w;
    }
}

// 4x4 register-tile inner product over K=64: acc[i][j] += At[k][4r+i]*Wt[k][4c+j]
#define TILE_MM(At, Wt, acc, r, c, KDIM)                                      \
    for (int k = 0; k < KDIM; k++) {                                          \
        f4 a = *(const f4*)&(At)[k * PITCH + (r) * 4];                        \
        f4 w = *(const f4*)&(Wt)[k * PITCH + (c) * 4];                        \
        acc[0][0] = fmaf(a.x, w.x, acc[0][0]);                                \
        acc[0][1] = fmaf(a.x, w.y, acc[0][1]);                                \
        acc[0][2] = fmaf(a.x, w.z, acc[0][2]);                                \
        acc[0][3] = fmaf(a.x, w.w, acc[0][3]);                                \
        acc[1][0] = fmaf(a.y, w.x, acc[1][0]);                                \
        acc[1][1] = fmaf(a.y, w.y, acc[1][1]);                                \
        acc[1][2] = fmaf(a.y, w.z, acc[1][2]);                                \
        acc[1][3] = fmaf(a.y, w.w, acc[1][3]);                                \
        acc[2][0] = fmaf(a.z, w.x, acc[2][0]);                                \
        acc[2][1] = fmaf(a.z, w.y, acc[2][1]);                                \
        acc[2][2] = fmaf(a.z, w.z, acc[2][2]);                                \
        acc[2][3] = fmaf(a.z, w.w, acc[2][3]);                                \
        acc[3][0] = fmaf(a.w, w.x, acc[3][0]);                                \
        acc[3][1] = fmaf(a.w, w.y, acc[3][1]);                                \
        acc[3][2] = fmaf(a.w, w.z, acc[3][2]);                                \
        acc[3][3] = fmaf(a.w, w.w, acc[3][3]);                                \
    }

// ---------------- SAGE dense: Yl = h@Wl.T ; Zr = h@Wr.T + bl ----------------

__global__ __launch_bounds__(256) void sage_dense(const f4* __restrict__ h4,
                                                  const float* __restrict__ Wl,
                                                  const float* __restrict__ bl,
                                                  const float* __restrict__ Wr,
                                                  f4* __restrict__ Yl4,
                                                  f4* __restrict__ Zr4, int n) {
    __shared__ float At[64 * PITCH];
    __shared__ float Wt[64 * PITCH];
    int t = threadIdx.x;
    int nb = blockIdx.x * 64;
    int r = t & 15, c = t >> 4;
    stageT(At, h4 + (size_t)nb * 16, t, n - nb);
    stageT(Wt, (const f4*)Wl, t, 64);
    __syncthreads();
    {
        float acc[4][4] = {{0.f}};
        TILE_MM(At, Wt, acc, r, c, 64)
#pragma unroll
        for (int i = 0; i < 4; i++) {
            int node = nb + r * 4 + i;
            if (node < n)
                Yl4[(size_t)node * 16 + c] =
                    make_float4(acc[i][0], acc[i][1], acc[i][2], acc[i][3]);
        }
    }
    __syncthreads();
    stageT(Wt, (const f4*)Wr, t, 64);
    __syncthreads();
    {
        float acc[4][4] = {{0.f}};
        TILE_MM(At, Wt, acc, r, c, 64)
        f4 bv = ((const f4*)bl)[c];
#pragma unroll
        for (int i = 0; i < 4; i++) {
            int node = nb + r * 4 + i;
            if (node < n)
                Zr4[(size_t)node * 16 + c] =
                    make_float4(acc[i][0] + bv.x, acc[i][1] + bv.y,
                                acc[i][2] + bv.z, acc[i][3] + bv.w);
        }
    }
}

// ---------------- GAT dense: ht = h@W.T ; as = ht.a_src ; ad = ht.a_dst ----------------

__global__ __launch_bounds__(256) void gat_transform(const f4* __restrict__ h4,
                                                     const float* __restrict__ W,
                                                     const float* __restrict__ a_src,
                                                     const float* __restrict__ a_dst,
                                                     f4* __restrict__ ht4,
                                                     float* __restrict__ as_,
                                                     float* __restrict__ ad_, int n) {
    __shared__ float At[64 * PITCH];
    __shared__ float Wt[64 * PITCH];
    __shared__ float ps[16][68];
    __shared__ float pd[16][68];
    int t = threadIdx.x;
    int nb = blockIdx.x * 64;
    int r = t & 15, c = t >> 4;
    stageT(At, h4 + (size_t)nb * 16, t, n - nb);
    stageT(Wt, (const f4*)W, t, 64);
    __syncthreads();
    float acc[4][4] = {{0.f}};
    TILE_MM(At, Wt, acc, r, c, 64)
    f4 sv = ((const f4*)a_src)[c];
    f4 dv = ((const f4*)a_dst)[c];
#pragma unroll
    for (int i = 0; i < 4; i++) {
        int node = nb + r * 4 + i;
        if (node < n)
            ht4[(size_t)node * 16 + c] =
                make_float4(acc[i][0], acc[i][1], acc[i][2], acc[i][3]);
        ps[c][r * 4 + i] = acc[i][0] * sv.x + acc[i][1] * sv.y +
                           acc[i][2] * sv.z + acc[i][3] * sv.w;
        pd[c][r * 4 + i] = acc[i][0] * dv.x + acc[i][1] * dv.y +
                           acc[i][2] * dv.z + acc[i][3] * dv.w;
    }
    __syncthreads();
    if (t < 64) {
        int node = nb + t;
        if (node < n) {
            float s = 0.f, d = 0.f;
#pragma unroll
            for (int cc = 0; cc < 16; cc++) {
                s += ps[cc][t];
                d += pd[cc][t];
            }
            as_[node] = s;
            ad_[node] = d;
        }
    }
}

// ---------------- SAGE gather: out = relu(mean_j Yl[j] + Zr[i]) ----------------

__global__ __launch_bounds__(256) void sage_gather(const f4* __restrict__ Yl,
                                                   const f4* __restrict__ Zr,
                                                   const int* __restrict__ rowptr,
                                                   const int* __restrict__ col,
                                                   f4* __restrict__ out,
                                                   int relu_flag, int n) {
    int t = blockIdx.x * 256 + threadIdx.x;
    int l16 = t & 15;
    int gbase = (threadIdx.x & 63) & 48;
    int stride = (gridDim.x * 256) >> 4;
    for (int node = t >> 4; node < n; node += stride) {
        int start = rowptr[node], end = rowptr[node + 1];
        f4 a0 = {0, 0, 0, 0}, a1 = {0, 0, 0, 0}, a2 = {0, 0, 0, 0}, a3 = {0, 0, 0, 0};
        for (int base = start; base < end; base += 16) {
            int idx = base + l16;
            int s_l = (idx < end) ? col[idx] : 0;
            int cnt = min(16, end - base);
            int i = 0;
            for (; i + 7 < cnt; i += 8) {
                int s0 = __shfl(s_l, gbase + i);
                int s1 = __shfl(s_l, gbase + i + 1);
                int s2 = __shfl(s_l, gbase + i + 2);
                int s3 = __shfl(s_l, gbase + i + 3);
                int s4 = __shfl(s_l, gbase + i + 4);
                int s5 = __shfl(s_l, gbase + i + 5);
                int s6 = __shfl(s_l, gbase + i + 6);
                int s7 = __shfl(s_l, gbase + i + 7);
                f4 r0 = Yl[(size_t)s0 * D4 + l16];
                f4 r1 = Yl[(size_t)s1 * D4 + l16];
                f4 r2 = Yl[(size_t)s2 * D4 + l16];
                f4 r3 = Yl[(size_t)s3 * D4 + l16];
                f4 r4 = Yl[(size_t)s4 * D4 + l16];
                f4 r5 = Yl[(size_t)s5 * D4 + l16];
                f4 r6 = Yl[(size_t)s6 * D4 + l16];
                f4 r7 = Yl[(size_t)s7 * D4 + l16];
                a0 = f4add(a0, r0); a1 = f4add(a1, r1);
                a2 = f4add(a2, r2); a3 = f4add(a3, r3);
                a0 = f4add(a0, r4); a1 = f4add(a1, r5);
                a2 = f4add(a2, r6); a3 = f4add(a3, r7);
            }
            for (; i < cnt; i++) {
                int s = __shfl(s_l, gbase + i);
                a0 = f4add(a0, Yl[(size_t)s * D4 + l16]);
            }
        }
        f4 a = f4add(f4add(a0, a1), f4add(a2, a3));
        float invd = 1.f / fmaxf((float)(end - start), 1.f);
        f4 z = Zr[(size_t)node * D4 + l16];
        f4 o = make_float4(fmaf(a.x, invd, z.x), fmaf(a.y, invd, z.y),
                           fmaf(a.z, invd, z.z), fmaf(a.w, invd, z.w));
        if (relu_flag) {
            o.x = fmaxf(o.x, 0.f); o.y = fmaxf(o.y, 0.f);
            o.z = fmaxf(o.z, 0.f); o.w = fmaxf(o.w, 0.f);
        }
        out[(size_t)node * D4 + l16] = o;
    }
}

// ---------------- GAT gather: single-pass online softmax + weighted agg ----------------

__global__ __launch_bounds__(256) void gat_gather(const int* __restrict__ rowptr,
                                                  const int* __restrict__ col,
                                                  const float* __restrict__ as_,
                                                  const float* __restrict__ ad_,
                                                  const f4* __restrict__ ht,
                                                  const float* __restrict__ b,
                                                  f4* __restrict__ out,
                                                  int relu_flag, int n) {
    int t = blockIdx.x * 256 + threadIdx.x;
    int l16 = t & 15;
    int gbase = (threadIdx.x & 63) & 48;
    int stride = (gridDim.x * 256) >> 4;
    const f4* b4 = (const f4*)b;
    for (int node = t >> 4; node < n; node += stride) {
        int start = rowptr[node], end = rowptr[node + 1];
        float ad_n = ad_[node];
        float e_self = leaky02(as_[node] + ad_n);
        float m = e_self;
        float z0 = 1.f, z1 = 0.f, z2 = 0.f, z3 = 0.f;
        f4 acc0 = ht[(size_t)node * D4 + l16];
        f4 acc1 = {0, 0, 0, 0}, acc2 = {0, 0, 0, 0}, acc3 = {0, 0, 0, 0};
        for (int base = start; base < end; base += 16) {
            int idx = base + l16;
            int cnt = min(16, end - base);
            int s_l = (idx < end) ? col[idx] : 0;
            float e_l = (idx < end) ? leaky02(as_[s_l] + ad_n) : -3.4e38f;
            float cm = e_l;
#pragma unroll
            for (int off = 8; off > 0; off >>= 1)
                cm = fmaxf(cm, __shfl_xor(cm, off));
            if (cm > m) {
                float sc = __expf(m - cm);
                z0 *= sc; z1 *= sc; z2 *= sc; z3 *= sc;
                acc0 = f4scale(acc0, sc); acc1 = f4scale(acc1, sc);
                acc2 = f4scale(acc2, sc); acc3 = f4scale(acc3, sc);
                m = cm;
            }
            float p_l = (idx < end) ? __expf(e_l - m) : 0.f;
            int i = 0;
            for (; i + 3 < cnt; i += 4) {
                int s0 = __shfl(s_l, gbase + i);
                int s1 = __shfl(s_l, gbase + i + 1);
                int s2 = __shfl(s_l, gbase + i + 2);
                int s3 = __shfl(s_l, gbase + i + 3);
                float p0 = __shfl(p_l, gbase + i);
                float p1 = __shfl(p_l, gbase + i + 1);
                float p2 = __shfl(p_l, gbase + i + 2);
                float p3 = __shfl(p_l, gbase + i + 3);
                f4 r0 = ht[(size_t)s0 * D4 + l16];
                f4 r1 = ht[(size_t)s1 * D4 + l16];
                f4 r2 = ht[(size_t)s2 * D4 + l16];
                f4 r3 = ht[(size_t)s3 * D4 + l16];
                z0 += p0; z1 += p1; z2 += p2; z3 += p3;
                acc0 = f4fma(p0, r0, acc0);
                acc1 = f4fma(p1, r1, acc1);
                acc2 = f4fma(p2, r2, acc2);
                acc3 = f4fma(p3, r3, acc3);
            }
            for (; i < cnt; i++) {
                int s0 = __shfl(s_l, gbase + i);
                float p0 = __shfl(p_l, gbase + i);
                z0 += p0;
                acc0 = f4fma(p0, ht[(size_t)s0 * D4 + l16], acc0);
            }
        }
        float rz = 1.f / ((z0 + z1) + (z2 + z3));
        f4 acc = f4add(f4add(acc0, acc1), f4add(acc2, acc3));
        f4 bb = b4[l16];
        f4 o = make_float4(fmaf(acc.x, rz, bb.x), fmaf(acc.y, rz, bb.y),
                           fmaf(acc.z, rz, bb.z), fmaf(acc.w, rz, bb.w));
        if (relu_flag) {
            o.x = fmaxf(o.x, 0.f); o.y = fmaxf(o.y, 0.f);
            o.z = fmaxf(o.z, 0.f); o.w = fmaxf(o.w, 0.f);
        }
        out[(size_t)node * D4 + l16] = o;
    }
}

// ---------------- MLP: tiled 3-layer chain in one kernel ----------------

__global__ __launch_bounds__(256) void mlp_kernel(const f4* __restrict__ h4,
                                                  const float* __restrict__ W1,
                                                  const float* __restrict__ b1,
                                                  const float* __restrict__ W2,
                                                  const float* __restrict__ b2,
                                                  const float* __restrict__ W3,
                                                  const float* __restrict__ b3,
                                                  float* __restrict__ out, int n) {
    __shared__ float At[64 * PITCH];   // h tile, then v1T
    __shared__ float Wt[64 * PITCH];   // W1t, then W2t, then W3t
    __shared__ float V2[32 * PITCH];   // v2T
    int t = threadIdx.x;
    int nb = blockIdx.x * 64;
    int r = t & 15, c = t >> 4;
    stageT(At, h4 + (size_t)nb * 16, t, n - nb);
    stageT(Wt, (const f4*)W1, t, 64);
    __syncthreads();
    // layer 1: 64 -> 64, relu
    float a1v[4][4] = {{0.f}};
    TILE_MM(At, Wt, a1v, r, c, 64)
    f4 b1v = ((const f4*)b1)[c];
    __syncthreads();   // done reading At (h), Wt (W1)
    {
        float bb[4] = {b1v.x, b1v.y, b1v.z, b1v.w};
#pragma unroll
        for (int i = 0; i < 4; i++)
#pragma unroll
            for (int j = 0; j < 4; j++)
                At[(c * 4 + j) * PITCH + r * 4 + i] = fmaxf(a1v[i][j] + bb[j], 0.f);
    }
    stageT(Wt, (const f4*)W2, t, 32);   // W2 is [32][64]
    __syncthreads();
    // layer 2: 64 -> 32, relu; thread owns 4 nodes x 2 outs (o = 2c, 2c+1)
    float a2v[4][2] = {{0.f}};
    for (int k = 0; k < 64; k++) {
        f4 a = *(const f4*)&At[k * PITCH + r * 4];
        float w0 = Wt[k * PITCH + c * 2];
        float w1 = Wt[k * PITCH + c * 2 + 1];
        a2v[0][0] = fmaf(a.x, w0, a2v[0][0]); a2v[0][1] = fmaf(a.x, w1, a2v[0][1]);
        a2v[1][0] = fmaf(a.y, w0, a2v[1][0]); a2v[1][1] = fmaf(a.y, w1, a2v[1][1]);
        a2v[2][0] = fmaf(a.z, w0, a2v[2][0]); a2v[2][1] = fmaf(a.z, w1, a2v[2][1]);
        a2v[3][0] = fmaf(a.w, w0, a2v[3][0]); a2v[3][1] = fmaf(a.w, w1, a2v[3][1]);
    }
    float b20 = b2[c * 2], b21 = b2[c * 2 + 1];
    __syncthreads();   // done reading At (v1), Wt (W2)
#pragma unroll
    for (int i = 0; i < 4; i++) {
        V2[(c * 2 + 0) * PITCH + r * 4 + i] = fmaxf(a2v[i][0] + b20, 0.f);
        V2[(c * 2 + 1) * PITCH + r * 4 + i] = fmaxf(a2v[i][1] + b21, 0.f);
    }
    // stage W3t: W3 is [16][32] -> Wt[k<32][o<16]
    if (t < 128) {
        int row = t >> 3, kq = t & 7;
        f4 w = ((const f4*)W3)[row * 8 + kq];
        int k0 = kq * 4;
        Wt[(k0 + 0) * PITCH + row] = w.x;
        Wt[(k0 + 1) * PITCH + row] = w.y;
        Wt[(k0 + 2) * PITCH + row] = w.z;
        Wt[(k0 + 3) * PITCH + row] = w.w;
    }
    __syncthreads();
    // layer 3: 32 -> 16; thread owns 4 nodes x 1 out (o = c)
    float a3v[4] = {0.f, 0.f, 0.f, 0.f};
    for (int k = 0; k < 32; k++) {
        f4 a = *(const f4*)&V2[k * PITCH + r * 4];
        float w = Wt[k * PITCH + c];
        a3v[0] = fmaf(a.x, w, a3v[0]);
        a3v[1] = fmaf(a.y, w, a3v[1]);
        a3v[2] = fmaf(a.z, w, a3v[2]);
        a3v[3] = fmaf(a.w, w, a3v[3]);
    }
    float b3v = b3[c];
#pragma unroll
    for (int i = 0; i < 4; i++) {
        int node = nb + r * 4 + i;
        if (node < n) out[(size_t)node * 16 + c] = a3v[i] + b3v;
    }
}

// ---------------- launch ----------------

extern "C" void kernel_launch(void* const* d_in, const int* in_sizes, int n_in,
                              void* d_out, int out_size, void* d_ws, size_t ws_size,
                              hipStream_t stream) {
    const int n  = in_sizes[0] / D;      // 100000
    const int ne = in_sizes[1] / 2;      // 1600000

    const float* x        = (const float*)d_in[0];
    const int*   ei       = (const int*)d_in[1];
    const int*   src      = ei;
    const int*   dst      = ei + ne;
    const float* sage_Wl  = (const float*)d_in[2];
    const float* sage_bl  = (const float*)d_in[3];
    const float* sage_Wr  = (const float*)d_in[4];
    const float* gat_W    = (const float*)d_in[5];
    const float* gat_asrc = (const float*)d_in[6];
    const float* gat_adst = (const float*)d_in[7];
    const float* gat_b    = (const float*)d_in[8];
    const float* W1 = (const float*)d_in[9];
    const float* b1 = (const float*)d_in[10];
    const float* W2 = (const float*)d_in[11];
    const float* b2 = (const float*)d_in[12];
    const float* W3 = (const float*)d_in[13];
    const float* b3 = (const float*)d_in[14];
    float* out = (float*)d_out;

    // workspace layout (4B units, all offsets 16B-aligned)
    int*   cnt      = (int*)d_ws;                    // n
    int*   incl     = cnt + n;                       // n
    int*   rowptr   = incl + n;                      // n+4
    int*   cursor   = rowptr + n + 4;                // n
    int*   partials = cursor + n;                    // 1024
    int*   col      = partials + 1024;               // ne
    float* as_      = (float*)(col + ne);            // n
    float* ad_      = as_ + n;                       // n
    float* Yl       = ad_ + n;                       // n*D (also GAT ht)
    float* Zr       = Yl + (size_t)n * D;            // n*D
    float* bufA     = Zr + (size_t)n * D;            // n*D
    float* bufB     = bufA + (size_t)n * D;          // n*D

    const int gridE  = (ne + 255) / 256;
    const int nb     = (n + SCAN_BS - 1) / SCAN_BS;
    const int gridG  = (n * 16 + 255) / 256;         // 16 lanes per node
    const int gridM  = (n + 63) / 64;                // 64-node tiles

    // ---- CSR build ----
    hipMemsetAsync(cnt, 0, (size_t)n * 4, stream);
    hist_kernel<<<gridE, 256, 0, stream>>>(dst, cnt, ne);
    scan1_kernel<<<nb, SCAN_BS, 0, stream>>>(cnt, incl, partials, n);
    scan2_kernel<<<1, 1024, 0, stream>>>(partials, nb);
    scan3_kernel<<<nb, SCAN_BS, 0, stream>>>(cnt, incl, partials, rowptr, cursor, n, ne);
    fill_kernel<<<gridE, 256, 0, stream>>>(src, dst, cursor, col, ne);

    // ---- 4 SAGE layers (x -> A -> B -> A -> B) ----
    const float* cur = x;
    float* nxt = bufA;
    for (int l = 0; l < 4; l++) {
        sage_dense<<<gridM, 256, 0, stream>>>((const f4*)cur,
                                              sage_Wl + (size_t)l * D * D,
                                              sage_bl + (size_t)l * D,
                                              sage_Wr + (size_t)l * D * D,
                                              (f4*)Yl, (f4*)Zr, n);
        sage_gather<<<gridG, 256, 0, stream>>>((const f4*)Yl, (const f4*)Zr,
                                               rowptr, col, (f4*)nxt,
                                               (l < 3) ? 1 : 0, n);
        cur = nxt;
        nxt = (nxt == bufA) ? bufB : bufA;
    }
    // cur == bufB

    // ---- 4 GAT layers (in-place on bufB, ht reuses Yl) ----
    float* gin = bufB;
    for (int l = 0; l < 4; l++) {
        gat_transform<<<gridM, 256, 0, stream>>>((const f4*)gin,
                                                 gat_W + (size_t)l * D * D,
                                                 gat_asrc + (size_t)l * D,
                                                 gat_adst + (size_t)l * D,
                                                 (f4*)Yl, as_, ad_, n);
        gat_gather<<<gridG, 256, 0, stream>>>(rowptr, col, as_, ad_,
                                              (const f4*)Yl,
                                              gat_b + (size_t)l * D, (f4*)gin,
                                              (l < 3) ? 1 : 0, n);
    }

    // ---- projection MLP ----
    mlp_kernel<<<gridM, 256, 0, stream>>>((const f4*)gin, W1, b1, W2, b2, W3, b3, out, n);
}